// Round 1
// baseline (3595.837 us; speedup 1.0000x reference)
//
#include <hip/hip_runtime.h>
#include <math.h>

#define NUV 200000
#define NIV 100000
#define EV  1000000
#define NQV 100000

enum { MODE_STORE = 0, MODE_MAX = 1, MODE_MAX_RELU = 2, MODE_ADD = 3 };

// ---------------- degree count (float, exact for counts < 2^24) --------------
__global__ __launch_bounds__(256) void k_deg(const int* __restrict__ su,
                                             const int* __restrict__ di,
                                             float* __restrict__ deg_u,
                                             float* __restrict__ deg_i) {
    int e = blockIdx.x * 256 + threadIdx.x;
    if (e < EV) {
        atomicAdd(&deg_u[su[e]], 1.0f);
        atomicAdd(&deg_i[di[e]], 1.0f);
    }
}

// ---------------- deg -> 1/sqrt(deg) in place --------------------------------
__global__ __launch_bounds__(256) void k_inv(float* __restrict__ d, int n) {
    int i = blockIdx.x * 256 + threadIdx.x;
    if (i < n) {
        float v = d[i];
        d[i] = (v > 0.0f) ? (1.0f / sqrtf(v)) : 0.0f;
    }
}

// ---------------- per-edge symmetric norm ------------------------------------
__global__ __launch_bounds__(256) void k_norm(const int* __restrict__ su,
                                              const int* __restrict__ di,
                                              const float* __restrict__ inv_u,
                                              const float* __restrict__ inv_i,
                                              float* __restrict__ nrm) {
    int e = blockIdx.x * 256 + threadIdx.x;
    if (e < EV) nrm[e] = inv_u[su[e]] * inv_i[di[e]];
}

// ---------------- scatter: agg[dst] += x[src] * norm -------------------------
// one wave (64 lanes) per edge, lane = feature index
__global__ __launch_bounds__(256) void k_scatter(const float* __restrict__ x,
                                                 const int* __restrict__ src,
                                                 const int* __restrict__ dst,
                                                 const float* __restrict__ nrm,
                                                 float* __restrict__ agg) {
    size_t t = (size_t)blockIdx.x * 256 + threadIdx.x;
    int e = (int)(t >> 6);
    int f = (int)(t & 63);
    if (e < EV) {
        int s = src[e];
        int d = dst[e];
        float v = x[(size_t)s * 64 + f] * nrm[e];
        atomicAdd(&agg[(size_t)d * 64 + f], v);
    }
}

// ---------------- transform: out (op)= A @ W + b -----------------------------
// 16 rows x 64 cols per block of 256 threads; W staged in LDS.
__global__ __launch_bounds__(256) void k_transform(const float* __restrict__ A,
                                                   const float* __restrict__ W,
                                                   const float* __restrict__ b,
                                                   float* __restrict__ out,
                                                   int n, int mode) {
    __shared__ float sW[64 * 64];
    __shared__ float sA[16 * 64];
    for (int i = threadIdx.x; i < 4096; i += 256) sW[i] = W[i];
    int r0 = blockIdx.x * 16;
    for (int i = threadIdx.x * 4; i < 16 * 64; i += 256 * 4) {
        int rr = i >> 6;
        int row = r0 + rr;
        float4 v = make_float4(0.f, 0.f, 0.f, 0.f);
        if (row < n) v = *(const float4*)&A[(size_t)row * 64 + (i & 63)];
        *(float4*)&sA[i] = v;
    }
    __syncthreads();
    int r = threadIdx.x >> 4;   // 0..15 row in tile
    int jq = threadIdx.x & 15;  // 0..15 -> cols jq*4 .. jq*4+3
    int row = r0 + r;
    float4 bb = *(const float4*)&b[jq * 4];
    float a0 = bb.x, a1 = bb.y, a2 = bb.z, a3 = bb.w;
    #pragma unroll
    for (int c = 0; c < 64; c++) {
        float a = sA[r * 64 + c];
        float4 w = *(const float4*)&sW[c * 64 + jq * 4];
        a0 = fmaf(a, w.x, a0);
        a1 = fmaf(a, w.y, a1);
        a2 = fmaf(a, w.z, a2);
        a3 = fmaf(a, w.w, a3);
    }
    if (row < n) {
        float* o = &out[(size_t)row * 64 + jq * 4];
        if (mode == MODE_STORE) {
            o[0] = a0; o[1] = a1; o[2] = a2; o[3] = a3;
        } else if (mode == MODE_MAX) {
            o[0] = fmaxf(o[0], a0); o[1] = fmaxf(o[1], a1);
            o[2] = fmaxf(o[2], a2); o[3] = fmaxf(o[3], a3);
        } else if (mode == MODE_MAX_RELU) {
            o[0] = fmaxf(fmaxf(o[0], a0), 0.f);
            o[1] = fmaxf(fmaxf(o[1], a1), 0.f);
            o[2] = fmaxf(fmaxf(o[2], a2), 0.f);
            o[3] = fmaxf(fmaxf(o[3], a3), 0.f);
        } else {  // MODE_ADD
            o[0] += a0; o[1] += a1; o[2] += a2; o[3] += a3;
        }
    }
}

// ---------------- decoder: wave per query ------------------------------------
__global__ __launch_bounds__(256) void k_decoder(const float* __restrict__ xu,
                                                 const float* __restrict__ xi,
                                                 const int* __restrict__ uids,
                                                 const int* __restrict__ iids,
                                                 const float* __restrict__ w1,
                                                 const float* __restrict__ b1,
                                                 const float* __restrict__ w2,
                                                 const float* __restrict__ b2,
                                                 float* __restrict__ out) {
    __shared__ float sW1[128 * 64];  // 32 KB
    __shared__ float sW2[64 * 4];
    __shared__ float sB1[64];
    __shared__ float sB2[4];
    for (int i = threadIdx.x; i < 128 * 64; i += 256) sW1[i] = w1[i];
    for (int i = threadIdx.x; i < 256; i += 256) sW2[i] = w2[i];
    if (threadIdx.x < 64) sB1[threadIdx.x] = b1[threadIdx.x];
    if (threadIdx.x < 4) sB2[threadIdx.x] = b2[threadIdx.x];
    __syncthreads();

    int wave = threadIdx.x >> 6;
    int lane = threadIdx.x & 63;
    int q = blockIdx.x * 4 + wave;
    if (q >= NQV) return;

    int uid = uids[q];
    int iid = iids[q];
    float eu = xu[(size_t)uid * 64 + lane];
    float ei = xi[(size_t)iid * 64 + lane];

    float acc = sB1[lane];
    #pragma unroll
    for (int c = 0; c < 64; c++) {
        float a = __shfl(eu, c, 64);
        acc = fmaf(a, sW1[c * 64 + lane], acc);
    }
    #pragma unroll
    for (int c = 0; c < 64; c++) {
        float a = __shfl(ei, c, 64);
        acc = fmaf(a, sW1[(64 + c) * 64 + lane], acc);
    }
    float h = fmaxf(acc, 0.f);

    float p0 = h * sW2[lane * 4 + 0];
    float p1 = h * sW2[lane * 4 + 1];
    float p2 = h * sW2[lane * 4 + 2];
    float p3 = h * sW2[lane * 4 + 3];
    #pragma unroll
    for (int off = 32; off; off >>= 1) {
        p0 += __shfl_xor(p0, off, 64);
        p1 += __shfl_xor(p1, off, 64);
        p2 += __shfl_xor(p2, off, 64);
        p3 += __shfl_xor(p3, off, 64);
    }
    if (lane == 0) {
        float* o = &out[(size_t)q * 4];
        o[0] = p0 + sB2[0];
        o[1] = p1 + sB2[1];
        o[2] = p2 + sB2[2];
        o[3] = p3 + sB2[3];
    }
}

extern "C" void kernel_launch(void* const* d_in, const int* in_sizes, int n_in,
                              void* d_out, int out_size, void* d_ws, size_t ws_size,
                              hipStream_t stream) {
    const float* user_emb = (const float*)d_in[0];
    const float* item_emb = (const float*)d_in[1];
    const float* W1 = (const float*)d_in[2];
    const float* b1 = (const float*)d_in[3];
    const float* W2 = (const float*)d_in[4];
    const float* b2 = (const float*)d_in[5];
    const float* dw1 = (const float*)d_in[6];
    const float* db1 = (const float*)d_in[7];
    const float* dw2 = (const float*)d_in[8];
    const float* db2 = (const float*)d_in[9];
    const int* edges[3] = {(const int*)d_in[10], (const int*)d_in[11], (const int*)d_in[12]};
    const int* uids = (const int*)d_in[13];
    const int* iids = (const int*)d_in[14];
    float* out = (float*)d_out;

    // workspace layout (floats)
    float* ws = (float*)d_ws;
    size_t off = 0;
    float* inv_u = ws + off; off += (size_t)3 * NUV;      // 600000
    float* inv_i = ws + off; off += (size_t)3 * NIV;      // 300000
    float* nrm[3];
    for (int r = 0; r < 3; r++) { nrm[r] = ws + off; off += (size_t)EV; }
    float* xu1 = ws + off; off += (size_t)NUV * 64;
    float* xi1 = ws + off; off += (size_t)NIV * 64;
    float* xu2 = ws + off; off += (size_t)NUV * 64;
    float* xi2 = ws + off; off += (size_t)NIV * 64;
    float* agg = ws + off; off += (size_t)NUV * 64;
    (void)ws_size; (void)in_sizes; (void)n_in; (void)out_size;

    const int EB = (EV + 255) / 256;           // edge-parallel blocks
    const int SB = (int)(((size_t)EV * 64) / 256);  // scatter blocks (64M/256)

    // degrees (zero first), inv-sqrt, per-edge norms
    hipMemsetAsync(inv_u, 0, (size_t)(3 * NUV + 3 * NIV) * sizeof(float), stream);
    for (int r = 0; r < 3; r++)
        k_deg<<<EB, 256, 0, stream>>>(edges[r], edges[r] + EV, inv_u + (size_t)r * NUV,
                                      inv_i + (size_t)r * NIV);
    k_inv<<<(3 * NUV + 3 * NIV + 255) / 256, 256, 0, stream>>>(inv_u, 3 * NUV + 3 * NIV);
    for (int r = 0; r < 3; r++)
        k_norm<<<EB, 256, 0, stream>>>(edges[r], edges[r] + EV, inv_u + (size_t)r * NUV,
                                       inv_i + (size_t)r * NIV, nrm[r]);

    // ---------------- layer 1 (max aggregation + relu) ----------------
    // user -> item : writes xi1 with W1[k], b1[k]
    for (int k = 0; k < 3; k++) {
        hipMemsetAsync(agg, 0, (size_t)NIV * 64 * sizeof(float), stream);
        k_scatter<<<SB, 256, 0, stream>>>(user_emb, edges[k], edges[k] + EV, nrm[k], agg);
        int mode = (k == 0) ? MODE_STORE : ((k == 2) ? MODE_MAX_RELU : MODE_MAX);
        k_transform<<<(NIV + 15) / 16, 256, 0, stream>>>(agg, W1 + (size_t)k * 4096,
                                                         b1 + (size_t)k * 64, xi1, NIV, mode);
    }
    // item -> user : writes xu1 with W1[k+3], b1[k+3]
    for (int k = 0; k < 3; k++) {
        hipMemsetAsync(agg, 0, (size_t)NUV * 64 * sizeof(float), stream);
        k_scatter<<<SB, 256, 0, stream>>>(item_emb, edges[k] + EV, edges[k], nrm[k], agg);
        int mode = (k == 0) ? MODE_STORE : ((k == 2) ? MODE_MAX_RELU : MODE_MAX);
        k_transform<<<(NUV + 15) / 16, 256, 0, stream>>>(agg, W1 + (size_t)(k + 3) * 4096,
                                                         b1 + (size_t)(k + 3) * 64, xu1, NUV, mode);
    }

    // ---------------- layer 2 (sum aggregation, no relu) ----------------
    // user -> item : xu1 -> xi2 with W2[k], b2[k]
    for (int k = 0; k < 3; k++) {
        hipMemsetAsync(agg, 0, (size_t)NIV * 64 * sizeof(float), stream);
        k_scatter<<<SB, 256, 0, stream>>>(xu1, edges[k], edges[k] + EV, nrm[k], agg);
        int mode = (k == 0) ? MODE_STORE : MODE_ADD;
        k_transform<<<(NIV + 15) / 16, 256, 0, stream>>>(agg, W2 + (size_t)k * 4096,
                                                         b2 + (size_t)k * 64, xi2, NIV, mode);
    }
    // item -> user : xi1 -> xu2 with W2[k+3], b2[k+3]
    for (int k = 0; k < 3; k++) {
        hipMemsetAsync(agg, 0, (size_t)NUV * 64 * sizeof(float), stream);
        k_scatter<<<SB, 256, 0, stream>>>(xi1, edges[k] + EV, edges[k], nrm[k], agg);
        int mode = (k == 0) ? MODE_STORE : MODE_ADD;
        k_transform<<<(NUV + 15) / 16, 256, 0, stream>>>(agg, W2 + (size_t)(k + 3) * 4096,
                                                         b2 + (size_t)(k + 3) * 64, xu2, NUV, mode);
    }

    // ---------------- decoder ----------------
    k_decoder<<<(NQV + 3) / 4, 256, 0, stream>>>(xu2, xi2, uids, iids, dw1, db1, dw2, db2, out);
}

// Round 2
// 2165.268 us; speedup vs baseline: 1.6607x; 1.6607x over previous
//
#include <hip/hip_runtime.h>
#include <math.h>

#define NUV 200000
#define NIV 100000
#define EV  1000000
#define NQV 100000
#define NC  (3 * NIV + 3 * NUV)   // 900000 concatenated degree/bucket counters
// bucket layout: [rel0 items][rel1 items][rel2 items][rel0 users][rel1 users][rel2 users]

// ---------------- histogram: count edges per (relation, dst-node) ------------
__global__ __launch_bounds__(256) void k_count(const int* __restrict__ su,
                                               const int* __restrict__ di,
                                               int* __restrict__ cnt, int k) {
    int e = blockIdx.x * 256 + threadIdx.x;
    if (e < EV) {
        atomicAdd(&cnt[k * NIV + di[e]], 1);
        atomicAdd(&cnt[3 * NIV + k * NUV + su[e]], 1);
    }
}

// ---------------- counts -> 1/sqrt(deg) --------------------------------------
__global__ __launch_bounds__(256) void k_invf(const int* __restrict__ cnt,
                                              float* __restrict__ invs) {
    int i = blockIdx.x * 256 + threadIdx.x;
    if (i < NC) {
        int c = cnt[i];
        invs[i] = (c > 0) ? (1.0f / sqrtf((float)c)) : 0.0f;
    }
}

// ---------------- scan stage 1: per-256 tile exclusive scan ------------------
__global__ __launch_bounds__(256) void k_scan1(const int* __restrict__ cnt,
                                               int* __restrict__ S,
                                               int* __restrict__ bsum) {
    __shared__ int tmp[256];
    int idx = blockIdx.x * 256 + threadIdx.x;
    int v = (idx < NC) ? cnt[idx] : 0;
    tmp[threadIdx.x] = v;
    __syncthreads();
    for (int off = 1; off < 256; off <<= 1) {
        int t = (threadIdx.x >= off) ? tmp[threadIdx.x - off] : 0;
        __syncthreads();
        tmp[threadIdx.x] += t;
        __syncthreads();
    }
    if (idx < NC) S[idx] = tmp[threadIdx.x] - v;
    if (threadIdx.x == 255) bsum[blockIdx.x] = tmp[255];
}

// ---------------- scan stage 2: single-wave scan of block sums ---------------
__global__ __launch_bounds__(64) void k_scan2(int* __restrict__ bsum, int nb) {
    int lane = threadIdx.x;
    int carry = 0;
    for (int base = 0; base < nb; base += 64) {
        int i = base + lane;
        int v = (i < nb) ? bsum[i] : 0;
        int orig = v;
        #pragma unroll
        for (int off = 1; off < 64; off <<= 1) {
            int t = __shfl_up(v, off, 64);
            if (lane >= off) v += t;
        }
        if (i < nb) bsum[i] = carry + v - orig;  // exclusive
        carry += __shfl(v, 63, 64);
    }
}

// ---------------- scan stage 3: add block offsets, write sentinel ------------
__global__ __launch_bounds__(256) void k_scan3(int* __restrict__ S,
                                               const int* __restrict__ bsum) {
    int idx = blockIdx.x * 256 + threadIdx.x;
    if (idx < NC) S[idx] += bsum[blockIdx.x];
    if (idx == 0) S[NC] = 6 * EV;
}

// ---------------- fill CSR entries: (src, norm) packed as float2 -------------
__global__ __launch_bounds__(256) void k_fill(const int* __restrict__ su,
                                              const int* __restrict__ di,
                                              const float* __restrict__ invs,
                                              int* __restrict__ cur,
                                              float2* __restrict__ ent, int k) {
    int e = blockIdx.x * 256 + threadIdx.x;
    if (e < EV) {
        int u = su[e], i = di[e];
        float nm = invs[k * NIV + i] * invs[3 * NIV + k * NUV + u];
        int p1 = atomicAdd(&cur[k * NIV + i], 1);
        ent[p1] = make_float2(__int_as_float(u), nm);
        int p2 = atomicAdd(&cur[3 * NIV + k * NUV + u], 1);
        ent[p2] = make_float2(__int_as_float(i), nm);
    }
}

// ---------------- fused gather-aggregate + transform + hetero combine --------
// 16 dst nodes per block (4 waves x 4 nodes). Per relation k:
//   stage W_k (16 KB) in LDS; wave gathers x[src]*norm rows into sAcc;
//   256 threads = 16 rows x 16 col-groups compute y_k = acc @ W_k + b_k;
//   combine across k in registers (mode 0: relu(max), mode 1: sum).
__global__ __launch_bounds__(256) void k_agg(const float* __restrict__ x,
                                             const float2* __restrict__ ent,
                                             const int* __restrict__ S,
                                             int seg_base, int n_dst,
                                             const float* __restrict__ Wb,
                                             const float* __restrict__ bb,
                                             float* __restrict__ out, int mode) {
    __shared__ float sW[4096];        // 64x64 weights for current relation
    __shared__ float sAcc[16 * 68];   // 16 rows, stride 68 (bank-conflict pad)
    int wave = threadIdx.x >> 6;
    int lane = threadIdx.x & 63;
    int r2 = threadIdx.x >> 4;        // 0..15 row for transform phase
    int g  = threadIdx.x & 15;        // col group (4 cols)
    int d0 = blockIdx.x * 16;

    float4 res = make_float4(0.f, 0.f, 0.f, 0.f);
    for (int k = 0; k < 3; k++) {
        __syncthreads();  // protect sW/sAcc from previous iteration's readers
        // stage W_k
        {
            const float4* wsrc = (const float4*)(Wb + (size_t)k * 4096);
            float4* wdst = (float4*)sW;
            #pragma unroll
            for (int i = 0; i < 4; i++) wdst[threadIdx.x + 256 * i] = wsrc[threadIdx.x + 256 * i];
        }
        // gather-aggregate 4 nodes per wave
        for (int q = 0; q < 4; q++) {
            int r = wave * 4 + q;
            int d = d0 + r;
            float acc0 = 0.f, acc1 = 0.f;
            if (d < n_dst) {
                int idx = seg_base + k * n_dst + d;
                int st = S[idx], en = S[idx + 1];
                int p = st;
                for (; p + 2 <= en; p += 2) {
                    float2 e0 = ent[p], e1 = ent[p + 1];
                    int s0 = __float_as_int(e0.x);
                    int s1 = __float_as_int(e1.x);
                    acc0 = fmaf(x[(size_t)s0 * 64 + lane], e0.y, acc0);
                    acc1 = fmaf(x[(size_t)s1 * 64 + lane], e1.y, acc1);
                }
                if (p < en) {
                    float2 e0 = ent[p];
                    acc0 = fmaf(x[(size_t)__float_as_int(e0.x) * 64 + lane], e0.y, acc0);
                }
            }
            sAcc[r * 68 + lane] = acc0 + acc1;
        }
        __syncthreads();
        // transform: y_k = acc @ W_k + b_k for this thread's (row r2, cols g*4..+3)
        float4 y = *(const float4*)&bb[k * 64 + g * 4];
        #pragma unroll
        for (int c = 0; c < 64; c++) {
            float a = sAcc[r2 * 68 + c];
            float4 w = *(const float4*)&sW[c * 64 + g * 4];
            y.x = fmaf(a, w.x, y.x);
            y.y = fmaf(a, w.y, y.y);
            y.z = fmaf(a, w.z, y.z);
            y.w = fmaf(a, w.w, y.w);
        }
        if (k == 0) {
            res = y;
        } else if (mode == 0) {
            res.x = fmaxf(res.x, y.x); res.y = fmaxf(res.y, y.y);
            res.z = fmaxf(res.z, y.z); res.w = fmaxf(res.w, y.w);
        } else {
            res.x += y.x; res.y += y.y; res.z += y.z; res.w += y.w;
        }
    }
    if (mode == 0) {
        res.x = fmaxf(res.x, 0.f); res.y = fmaxf(res.y, 0.f);
        res.z = fmaxf(res.z, 0.f); res.w = fmaxf(res.w, 0.f);
    }
    int d = d0 + r2;
    if (d < n_dst) *(float4*)&out[(size_t)d * 64 + g * 4] = res;
}

// ---------------- decoder: 16 queries per block, tile GEMM -------------------
__global__ __launch_bounds__(256) void k_decoder(const float* __restrict__ xu,
                                                 const float* __restrict__ xi,
                                                 const int* __restrict__ uids,
                                                 const int* __restrict__ iids,
                                                 const float* __restrict__ w1,
                                                 const float* __restrict__ b1,
                                                 const float* __restrict__ w2,
                                                 const float* __restrict__ b2,
                                                 float* __restrict__ out) {
    __shared__ float sW1[128 * 64];   // 32 KB
    __shared__ float sE[16 * 132];    // 16 gathered 128-dim rows, padded
    __shared__ float sH[16 * 68];     // hidden after relu, padded
    __shared__ float sW2[64 * 4];
    // stage weights
    {
        const float4* wsrc = (const float4*)w1;
        float4* wdst = (float4*)sW1;
        #pragma unroll
        for (int i = 0; i < 8; i++) wdst[threadIdx.x + 256 * i] = wsrc[threadIdx.x + 256 * i];
        if (threadIdx.x < 64) {
            float4 v = ((const float4*)w2)[threadIdx.x];
            ((float4*)sW2)[threadIdx.x] = v;
        }
    }
    int q0 = blockIdx.x * 16;
    // gather 16 query rows (user 64 + item 64) into sE
    {
        int q = threadIdx.x >> 4;     // 0..15
        int p = threadIdx.x & 15;     // 0..15 float4s
        int uid = uids[q0 + q];
        int iid = iids[q0 + q];
        float4 vu = *(const float4*)&xu[(size_t)uid * 64 + p * 4];
        float4 vi = *(const float4*)&xi[(size_t)iid * 64 + p * 4];
        *(float4*)&sE[q * 132 + p * 4] = vu;
        *(float4*)&sE[q * 132 + 64 + p * 4] = vi;
    }
    __syncthreads();
    // layer 1: h = relu(E @ W1 + b1); thread = (row r, col group g)
    {
        int r = threadIdx.x >> 4;
        int g = threadIdx.x & 15;
        float4 y = *(const float4*)&b1[g * 4];
        #pragma unroll
        for (int c = 0; c < 128; c++) {
            float a = sE[r * 132 + c];
            float4 w = *(const float4*)&sW1[c * 64 + g * 4];
            y.x = fmaf(a, w.x, y.x);
            y.y = fmaf(a, w.y, y.y);
            y.z = fmaf(a, w.z, y.z);
            y.w = fmaf(a, w.w, y.w);
        }
        y.x = fmaxf(y.x, 0.f); y.y = fmaxf(y.y, 0.f);
        y.z = fmaxf(y.z, 0.f); y.w = fmaxf(y.w, 0.f);
        *(float4*)&sH[r * 68 + g * 4] = y;
    }
    __syncthreads();
    // layer 2: out = H @ W2 + b2 ; 64 threads, one (query, out-col) each
    if (threadIdx.x < 64) {
        int q = threadIdx.x >> 2;
        int oc = threadIdx.x & 3;
        float acc = b2[oc];
        #pragma unroll
        for (int c = 0; c < 64; c++)
            acc = fmaf(sH[q * 68 + c], sW2[c * 4 + oc], acc);
        out[(size_t)(q0 + q) * 4 + oc] = acc;
    }
}

extern "C" void kernel_launch(void* const* d_in, const int* in_sizes, int n_in,
                              void* d_out, int out_size, void* d_ws, size_t ws_size,
                              hipStream_t stream) {
    const float* user_emb = (const float*)d_in[0];
    const float* item_emb = (const float*)d_in[1];
    const float* W1 = (const float*)d_in[2];
    const float* b1 = (const float*)d_in[3];
    const float* W2 = (const float*)d_in[4];
    const float* b2 = (const float*)d_in[5];
    const float* dw1 = (const float*)d_in[6];
    const float* db1 = (const float*)d_in[7];
    const float* dw2 = (const float*)d_in[8];
    const float* db2 = (const float*)d_in[9];
    const int* edges[3] = {(const int*)d_in[10], (const int*)d_in[11], (const int*)d_in[12]};
    const int* uids = (const int*)d_in[13];
    const int* iids = (const int*)d_in[14];
    float* out = (float*)d_out;
    (void)in_sizes; (void)n_in; (void)out_size; (void)ws_size;

    // workspace layout (4-byte units; all region sizes even -> float2 aligned)
    char* base = (char*)d_ws;
    size_t off = 0;
    int*    cnt  = (int*)(base + off); off += (size_t)NC * 4;
    int*    S    = (int*)(base + off); off += (size_t)(NC + 8) * 4;
    int*    cur  = (int*)(base + off); off += (size_t)(NC + 8) * 4;
    int*    bsum = (int*)(base + off); off += (size_t)4096 * 4;
    float*  invs = (float*)(base + off); off += (size_t)NC * 4;
    float2* ent  = (float2*)(base + off); off += (size_t)6 * EV * 8;
    float*  xu1  = (float*)(base + off); off += (size_t)NUV * 64 * 4;
    float*  xi1  = (float*)(base + off); off += (size_t)NIV * 64 * 4;
    float*  xu2  = (float*)(base + off); off += (size_t)NUV * 64 * 4;
    float*  xi2  = (float*)(base + off); off += (size_t)NIV * 64 * 4;

    const int EB  = (EV + 255) / 256;   // 3907
    const int SB1 = (NC + 255) / 256;   // 3516

    // ---- CSR build ----
    hipMemsetAsync(cnt, 0, (size_t)NC * 4, stream);
    for (int k = 0; k < 3; k++)
        k_count<<<EB, 256, 0, stream>>>(edges[k], edges[k] + EV, cnt, k);
    k_invf<<<SB1, 256, 0, stream>>>(cnt, invs);
    k_scan1<<<SB1, 256, 0, stream>>>(cnt, S, bsum);
    k_scan2<<<1, 64, 0, stream>>>(bsum, SB1);
    k_scan3<<<SB1, 256, 0, stream>>>(S, bsum);
    hipMemcpyAsync(cur, S, (size_t)NC * 4, hipMemcpyDeviceToDevice, stream);
    for (int k = 0; k < 3; k++)
        k_fill<<<EB, 256, 0, stream>>>(edges[k], edges[k] + EV, invs, cur, ent, k);

    // ---- layer 1 (max across relations, then relu) ----
    k_agg<<<NIV / 16, 256, 0, stream>>>(user_emb, ent, S, 0, NIV,
                                        W1, b1, xi1, 0);
    k_agg<<<NUV / 16, 256, 0, stream>>>(item_emb, ent, S, 3 * NIV, NUV,
                                        W1 + (size_t)3 * 4096, b1 + 192, xu1, 0);
    // ---- layer 2 (sum across relations) ----
    k_agg<<<NIV / 16, 256, 0, stream>>>(xu1, ent, S, 0, NIV,
                                        W2, b2, xi2, 1);
    k_agg<<<NUV / 16, 256, 0, stream>>>(xi1, ent, S, 3 * NIV, NUV,
                                        W2 + (size_t)3 * 4096, b2 + 192, xu2, 1);

    // ---- decoder ----
    k_decoder<<<NQV / 16, 256, 0, stream>>>(xu2, xi2, uids, iids,
                                            dw1, db1, dw2, db2, out);
}

// Round 3
// 1681.669 us; speedup vs baseline: 2.1383x; 1.2876x over previous
//
#include <hip/hip_runtime.h>
#include <math.h>

#define NUV 200000
#define NIV 100000
#define EV  1000000
#define NQV 100000
#define NC  (3 * NIV + 3 * NUV)   // 900000 concatenated degree/bucket counters
// bucket layout: [rel0 items][rel1 items][rel2 items][rel0 users][rel1 users][rel2 users]

// ---------------- histogram: count edges per (relation, dst-node) ------------
__global__ __launch_bounds__(256) void k_count(const int* __restrict__ su,
                                               const int* __restrict__ di,
                                               int* __restrict__ cnt, int k) {
    int e = blockIdx.x * 256 + threadIdx.x;
    if (e < EV) {
        atomicAdd(&cnt[k * NIV + di[e]], 1);
        atomicAdd(&cnt[3 * NIV + k * NUV + su[e]], 1);
    }
}

// ---------------- counts -> 1/sqrt(deg) --------------------------------------
__global__ __launch_bounds__(256) void k_invf(const int* __restrict__ cnt,
                                              float* __restrict__ invs) {
    int i = blockIdx.x * 256 + threadIdx.x;
    if (i < NC) {
        int c = cnt[i];
        invs[i] = (c > 0) ? (1.0f / sqrtf((float)c)) : 0.0f;
    }
}

// ---------------- scan stage 1: per-256 tile exclusive scan ------------------
__global__ __launch_bounds__(256) void k_scan1(const int* __restrict__ cnt,
                                               int* __restrict__ S,
                                               int* __restrict__ bsum) {
    __shared__ int tmp[256];
    int idx = blockIdx.x * 256 + threadIdx.x;
    int v = (idx < NC) ? cnt[idx] : 0;
    tmp[threadIdx.x] = v;
    __syncthreads();
    for (int off = 1; off < 256; off <<= 1) {
        int t = (threadIdx.x >= off) ? tmp[threadIdx.x - off] : 0;
        __syncthreads();
        tmp[threadIdx.x] += t;
        __syncthreads();
    }
    if (idx < NC) S[idx] = tmp[threadIdx.x] - v;
    if (threadIdx.x == 255) bsum[blockIdx.x] = tmp[255];
}

// ---------------- scan stage 2: single-wave scan of block sums ---------------
__global__ __launch_bounds__(64) void k_scan2(int* __restrict__ bsum, int nb) {
    int lane = threadIdx.x;
    int carry = 0;
    for (int base = 0; base < nb; base += 64) {
        int i = base + lane;
        int v = (i < nb) ? bsum[i] : 0;
        int orig = v;
        #pragma unroll
        for (int off = 1; off < 64; off <<= 1) {
            int t = __shfl_up(v, off, 64);
            if (lane >= off) v += t;
        }
        if (i < nb) bsum[i] = carry + v - orig;  // exclusive
        carry += __shfl(v, 63, 64);
    }
}

// ---------------- scan stage 3: add block offsets, write sentinel ------------
__global__ __launch_bounds__(256) void k_scan3(int* __restrict__ S,
                                               const int* __restrict__ bsum) {
    int idx = blockIdx.x * 256 + threadIdx.x;
    if (idx < NC) S[idx] += bsum[blockIdx.x];
    if (idx == 0) S[NC] = 6 * EV;
}

// ---------------- fill CSR entries: (src, norm) packed as float2 -------------
__global__ __launch_bounds__(256) void k_fill(const int* __restrict__ su,
                                              const int* __restrict__ di,
                                              const float* __restrict__ invs,
                                              int* __restrict__ cur,
                                              float2* __restrict__ ent, int k) {
    int e = blockIdx.x * 256 + threadIdx.x;
    if (e < EV) {
        int u = su[e], i = di[e];
        float nm = invs[k * NIV + i] * invs[3 * NIV + k * NUV + u];
        int p1 = atomicAdd(&cur[k * NIV + i], 1);
        ent[p1] = make_float2(__int_as_float(u), nm);
        int p2 = atomicAdd(&cur[3 * NIV + k * NUV + u], 1);
        ent[p2] = make_float2(__int_as_float(i), nm);
    }
}

// ---------------- fused gather-aggregate + transform + hetero combine --------
// One launch covers both directions: blocks [0, NIV/16) do items (u->i rels),
// blocks [NIV/16, NIV/16+NUV/16) do users (i->u rels).
// Per relation k: stage W_k in LDS; each wave gathers its 4 dst nodes
// CONCURRENTLY (lanes = 4 edge-subgroups x 16 float4-cols -> 16 row loads in
// flight); 2x shfl_xor reduce across subgroups; 256 threads = 16 rows x 16
// col-groups compute y_k = acc @ W_k + b_k; combine across k in registers.
__global__ __launch_bounds__(256) void k_agg(const float* __restrict__ x_i,   // src feats for item-side (users)
                                             const float* __restrict__ x_u,   // src feats for user-side (items)
                                             const float2* __restrict__ ent,
                                             const int* __restrict__ S,
                                             const float* __restrict__ Wall,  // [6,64,64]
                                             const float* __restrict__ ball,  // [6,64]
                                             float* __restrict__ out_i,
                                             float* __restrict__ out_u,
                                             int mode) {
    __shared__ float sW[4096];        // 64x64 weights for current relation
    __shared__ float sAcc[16 * 68];   // 16 rows, stride 68 (bank-conflict pad)
    const int nb_i = NIV / 16;
    bool item_side = blockIdx.x < nb_i;
    const float* x  = item_side ? x_i : x_u;
    const float* Wb = item_side ? Wall : Wall + 3 * 4096;
    const float* bb = item_side ? ball : ball + 192;
    float* outp     = item_side ? out_i : out_u;
    int n_dst       = item_side ? NIV : NUV;
    int seg_base    = item_side ? 0 : 3 * NIV;
    int d0          = (item_side ? blockIdx.x : (blockIdx.x - nb_i)) * 16;

    int wave = threadIdx.x >> 6;
    int lane = threadIdx.x & 63;
    int eg   = lane >> 4;             // edge subgroup 0..3
    int fq   = lane & 15;             // float4 column group 0..15
    int r2 = threadIdx.x >> 4;        // 0..15 row for transform phase
    int g  = threadIdx.x & 15;        // col group (4 cols)

    float4 res = make_float4(0.f, 0.f, 0.f, 0.f);
    for (int k = 0; k < 3; k++) {
        __syncthreads();  // protect sW/sAcc from previous iteration's readers
        // stage W_k
        {
            const float4* wsrc = (const float4*)(Wb + (size_t)k * 4096);
            float4* wdst = (float4*)sW;
            #pragma unroll
            for (int i = 0; i < 4; i++) wdst[threadIdx.x + 256 * i] = wsrc[threadIdx.x + 256 * i];
        }
        // gather-aggregate: this wave's 4 nodes concurrently
        {
            int idx = seg_base + k * n_dst + d0 + wave * 4;
            int v0 = S[idx], v1 = S[idx + 1], v2 = S[idx + 2], v3 = S[idx + 3], v4 = S[idx + 4];
            int st[4] = {v0, v1, v2, v3};
            int en[4] = {v1, v2, v3, v4};
            int maxlen = max(max(v1 - v0, v2 - v1), max(v3 - v2, v4 - v3));
            int maxit = (maxlen + 3) >> 2;
            float4 a[4];
            #pragma unroll
            for (int n = 0; n < 4; n++) a[n] = make_float4(0.f, 0.f, 0.f, 0.f);
            for (int it = 0; it < maxit; it++) {
                #pragma unroll
                for (int n = 0; n < 4; n++) {
                    int p = st[n] + (it << 2) + eg;
                    if (p < en[n]) {
                        float2 e = ent[p];
                        int s = __float_as_int(e.x);
                        float4 xv = *(const float4*)&x[(size_t)s * 64 + fq * 4];
                        a[n].x = fmaf(xv.x, e.y, a[n].x);
                        a[n].y = fmaf(xv.y, e.y, a[n].y);
                        a[n].z = fmaf(xv.z, e.y, a[n].z);
                        a[n].w = fmaf(xv.w, e.y, a[n].w);
                    }
                }
            }
            // reduce across the 4 edge-subgroups (lanes l, l^16, l^32, l^48)
            #pragma unroll
            for (int n = 0; n < 4; n++) {
                #pragma unroll
                for (int off = 16; off < 64; off <<= 1) {
                    a[n].x += __shfl_xor(a[n].x, off, 64);
                    a[n].y += __shfl_xor(a[n].y, off, 64);
                    a[n].z += __shfl_xor(a[n].z, off, 64);
                    a[n].w += __shfl_xor(a[n].w, off, 64);
                }
                if (lane < 16)
                    *(float4*)&sAcc[(wave * 4 + n) * 68 + fq * 4] = a[n];
            }
        }
        __syncthreads();
        // transform: y_k = acc @ W_k + b_k for this thread's (row r2, cols g*4..+3)
        float4 y = *(const float4*)&bb[k * 64 + g * 4];
        #pragma unroll
        for (int c = 0; c < 64; c++) {
            float a = sAcc[r2 * 68 + c];
            float4 w = *(const float4*)&sW[c * 64 + g * 4];
            y.x = fmaf(a, w.x, y.x);
            y.y = fmaf(a, w.y, y.y);
            y.z = fmaf(a, w.z, y.z);
            y.w = fmaf(a, w.w, y.w);
        }
        if (k == 0) {
            res = y;
        } else if (mode == 0) {
            res.x = fmaxf(res.x, y.x); res.y = fmaxf(res.y, y.y);
            res.z = fmaxf(res.z, y.z); res.w = fmaxf(res.w, y.w);
        } else {
            res.x += y.x; res.y += y.y; res.z += y.z; res.w += y.w;
        }
    }
    if (mode == 0) {
        res.x = fmaxf(res.x, 0.f); res.y = fmaxf(res.y, 0.f);
        res.z = fmaxf(res.z, 0.f); res.w = fmaxf(res.w, 0.f);
    }
    *(float4*)&outp[(size_t)(d0 + r2) * 64 + g * 4] = res;
}

// ---------------- decoder: 16 queries per block, tile GEMM -------------------
__global__ __launch_bounds__(256) void k_decoder(const float* __restrict__ xu,
                                                 const float* __restrict__ xi,
                                                 const int* __restrict__ uids,
                                                 const int* __restrict__ iids,
                                                 const float* __restrict__ w1,
                                                 const float* __restrict__ b1,
                                                 const float* __restrict__ w2,
                                                 const float* __restrict__ b2,
                                                 float* __restrict__ out) {
    __shared__ float sW1[128 * 64];   // 32 KB
    __shared__ float sE[16 * 132];    // 16 gathered 128-dim rows, padded
    __shared__ float sH[16 * 68];     // hidden after relu, padded
    __shared__ float sW2[64 * 4];
    // stage weights
    {
        const float4* wsrc = (const float4*)w1;
        float4* wdst = (float4*)sW1;
        #pragma unroll
        for (int i = 0; i < 8; i++) wdst[threadIdx.x + 256 * i] = wsrc[threadIdx.x + 256 * i];
        if (threadIdx.x < 64) {
            float4 v = ((const float4*)w2)[threadIdx.x];
            ((float4*)sW2)[threadIdx.x] = v;
        }
    }
    int q0 = blockIdx.x * 16;
    // gather 16 query rows (user 64 + item 64) into sE
    {
        int q = threadIdx.x >> 4;     // 0..15
        int p = threadIdx.x & 15;     // 0..15 float4s
        int uid = uids[q0 + q];
        int iid = iids[q0 + q];
        float4 vu = *(const float4*)&xu[(size_t)uid * 64 + p * 4];
        float4 vi = *(const float4*)&xi[(size_t)iid * 64 + p * 4];
        *(float4*)&sE[q * 132 + p * 4] = vu;
        *(float4*)&sE[q * 132 + 64 + p * 4] = vi;
    }
    __syncthreads();
    // layer 1: h = relu(E @ W1 + b1); thread = (row r, col group g)
    {
        int r = threadIdx.x >> 4;
        int g = threadIdx.x & 15;
        float4 y = *(const float4*)&b1[g * 4];
        #pragma unroll
        for (int c = 0; c < 128; c++) {
            float a = sE[r * 132 + c];
            float4 w = *(const float4*)&sW1[c * 64 + g * 4];
            y.x = fmaf(a, w.x, y.x);
            y.y = fmaf(a, w.y, y.y);
            y.z = fmaf(a, w.z, y.z);
            y.w = fmaf(a, w.w, y.w);
        }
        y.x = fmaxf(y.x, 0.f); y.y = fmaxf(y.y, 0.f);
        y.z = fmaxf(y.z, 0.f); y.w = fmaxf(y.w, 0.f);
        *(float4*)&sH[r * 68 + g * 4] = y;
    }
    __syncthreads();
    // layer 2: out = H @ W2 + b2 ; 64 threads, one (query, out-col) each
    if (threadIdx.x < 64) {
        int q = threadIdx.x >> 2;
        int oc = threadIdx.x & 3;
        float acc = b2[oc];
        #pragma unroll
        for (int c = 0; c < 64; c++)
            acc = fmaf(sH[q * 68 + c], sW2[c * 4 + oc], acc);
        out[(size_t)(q0 + q) * 4 + oc] = acc;
    }
}

extern "C" void kernel_launch(void* const* d_in, const int* in_sizes, int n_in,
                              void* d_out, int out_size, void* d_ws, size_t ws_size,
                              hipStream_t stream) {
    const float* user_emb = (const float*)d_in[0];
    const float* item_emb = (const float*)d_in[1];
    const float* W1 = (const float*)d_in[2];
    const float* b1 = (const float*)d_in[3];
    const float* W2 = (const float*)d_in[4];
    const float* b2 = (const float*)d_in[5];
    const float* dw1 = (const float*)d_in[6];
    const float* db1 = (const float*)d_in[7];
    const float* dw2 = (const float*)d_in[8];
    const float* db2 = (const float*)d_in[9];
    const int* edges[3] = {(const int*)d_in[10], (const int*)d_in[11], (const int*)d_in[12]};
    const int* uids = (const int*)d_in[13];
    const int* iids = (const int*)d_in[14];
    float* out = (float*)d_out;
    (void)in_sizes; (void)n_in; (void)out_size; (void)ws_size;

    // workspace layout (4-byte units; all region sizes even -> float2 aligned)
    char* base = (char*)d_ws;
    size_t off = 0;
    int*    cnt  = (int*)(base + off); off += (size_t)NC * 4;
    int*    S    = (int*)(base + off); off += (size_t)(NC + 8) * 4;
    int*    cur  = (int*)(base + off); off += (size_t)(NC + 8) * 4;
    int*    bsum = (int*)(base + off); off += (size_t)4096 * 4;
    float*  invs = (float*)(base + off); off += (size_t)NC * 4;
    float2* ent  = (float2*)(base + off); off += (size_t)6 * EV * 8;
    float*  xu1  = (float*)(base + off); off += (size_t)NUV * 64 * 4;
    float*  xi1  = (float*)(base + off); off += (size_t)NIV * 64 * 4;
    float*  xu2  = (float*)(base + off); off += (size_t)NUV * 64 * 4;
    float*  xi2  = (float*)(base + off); off += (size_t)NIV * 64 * 4;

    const int EB  = (EV + 255) / 256;   // 3907
    const int SB1 = (NC + 255) / 256;   // 3516
    const int AGGB = NIV / 16 + NUV / 16;  // 18750

    // ---- CSR build ----
    hipMemsetAsync(cnt, 0, (size_t)NC * 4, stream);
    for (int k = 0; k < 3; k++)
        k_count<<<EB, 256, 0, stream>>>(edges[k], edges[k] + EV, cnt, k);
    k_invf<<<SB1, 256, 0, stream>>>(cnt, invs);
    k_scan1<<<SB1, 256, 0, stream>>>(cnt, S, bsum);
    k_scan2<<<1, 64, 0, stream>>>(bsum, SB1);
    k_scan3<<<SB1, 256, 0, stream>>>(S, bsum);
    hipMemcpyAsync(cur, S, (size_t)NC * 4, hipMemcpyDeviceToDevice, stream);
    for (int k = 0; k < 3; k++)
        k_fill<<<EB, 256, 0, stream>>>(edges[k], edges[k] + EV, invs, cur, ent, k);

    // ---- layer 1 (max across relations, then relu): both directions ----
    k_agg<<<AGGB, 256, 0, stream>>>(user_emb, item_emb, ent, S, W1, b1, xi1, xu1, 0);
    // ---- layer 2 (sum across relations): both directions ----
    k_agg<<<AGGB, 256, 0, stream>>>(xu1, xi1, ent, S, W2, b2, xi2, xu2, 1);

    // ---- decoder ----
    k_decoder<<<NQV / 16, 256, 0, stream>>>(xu2, xi2, uids, iids,
                                            dw1, db1, dw2, db2, out);
}

// Round 4
// 1470.727 us; speedup vs baseline: 2.4449x; 1.1434x over previous
//
#include <hip/hip_runtime.h>
#include <hip/hip_fp16.h>
#include <math.h>

#define NUV 200000
#define NIV 100000
#define EV  1000000
#define NQV 100000
#define NC  (3 * NIV + 3 * NUV)   // 900000 concatenated degree/bucket counters
// bucket layout: [rel0 items][rel1 items][rel2 items][rel0 users][rel1 users][rel2 users]

struct alignas(8) H4 { __half2 a, b; };

// ---------------- fp32 -> fp16 table conversion ------------------------------
__global__ __launch_bounds__(256) void k_tohalf(const float* __restrict__ in,
                                                __half* __restrict__ out, int n4) {
    int i = blockIdx.x * 256 + threadIdx.x;
    if (i < n4) {
        float4 v = ((const float4*)in)[i];
        H4 o;
        o.a = __floats2half2_rn(v.x, v.y);
        o.b = __floats2half2_rn(v.z, v.w);
        ((H4*)out)[i] = o;
    }
}

// ---------------- histogram + in-bucket rank ---------------------------------
__global__ __launch_bounds__(256) void k_count(const int* __restrict__ su,
                                               const int* __restrict__ di,
                                               int* __restrict__ cnt,
                                               int* __restrict__ rk_i,
                                               int* __restrict__ rk_u, int k) {
    int e = blockIdx.x * 256 + threadIdx.x;
    if (e < EV) {
        rk_i[e] = atomicAdd(&cnt[k * NIV + di[e]], 1);
        rk_u[e] = atomicAdd(&cnt[3 * NIV + k * NUV + su[e]], 1);
    }
}

// ---------------- counts -> 1/sqrt(deg) --------------------------------------
__global__ __launch_bounds__(256) void k_invf(const int* __restrict__ cnt,
                                              float* __restrict__ invs) {
    int i = blockIdx.x * 256 + threadIdx.x;
    if (i < NC) {
        int c = cnt[i];
        invs[i] = (c > 0) ? (1.0f / sqrtf((float)c)) : 0.0f;
    }
}

// ---------------- scan stage 1: per-256 tile exclusive scan ------------------
__global__ __launch_bounds__(256) void k_scan1(const int* __restrict__ cnt,
                                               int* __restrict__ S,
                                               int* __restrict__ bsum) {
    __shared__ int tmp[256];
    int idx = blockIdx.x * 256 + threadIdx.x;
    int v = (idx < NC) ? cnt[idx] : 0;
    tmp[threadIdx.x] = v;
    __syncthreads();
    for (int off = 1; off < 256; off <<= 1) {
        int t = (threadIdx.x >= off) ? tmp[threadIdx.x - off] : 0;
        __syncthreads();
        tmp[threadIdx.x] += t;
        __syncthreads();
    }
    if (idx < NC) S[idx] = tmp[threadIdx.x] - v;
    if (threadIdx.x == 255) bsum[blockIdx.x] = tmp[255];
}

// ---------------- scan stage 2: single-wave scan of block sums ---------------
__global__ __launch_bounds__(64) void k_scan2(int* __restrict__ bsum, int nb) {
    int lane = threadIdx.x;
    int carry = 0;
    for (int base = 0; base < nb; base += 64) {
        int i = base + lane;
        int v = (i < nb) ? bsum[i] : 0;
        int orig = v;
        #pragma unroll
        for (int off = 1; off < 64; off <<= 1) {
            int t = __shfl_up(v, off, 64);
            if (lane >= off) v += t;
        }
        if (i < nb) bsum[i] = carry + v - orig;  // exclusive
        carry += __shfl(v, 63, 64);
    }
}

// ---------------- scan stage 3: add block offsets, write sentinel ------------
__global__ __launch_bounds__(256) void k_scan3(int* __restrict__ S,
                                               const int* __restrict__ bsum) {
    int idx = blockIdx.x * 256 + threadIdx.x;
    if (idx < NC) S[idx] += bsum[blockIdx.x];
    if (idx == 0) S[NC] = 6 * EV;
}

// ---------------- fill CSR entries via precomputed ranks (no atomics) --------
__global__ __launch_bounds__(256) void k_fill(const int* __restrict__ su,
                                              const int* __restrict__ di,
                                              const float* __restrict__ invs,
                                              const int* __restrict__ S,
                                              const int* __restrict__ rk_i,
                                              const int* __restrict__ rk_u,
                                              float2* __restrict__ ent, int k) {
    int e = blockIdx.x * 256 + threadIdx.x;
    if (e < EV) {
        int u = su[e], i = di[e];
        float nm = invs[k * NIV + i] * invs[3 * NIV + k * NUV + u];
        int p1 = S[k * NIV + i] + rk_i[e];
        ent[p1] = make_float2(__int_as_float(u), nm);
        int p2 = S[3 * NIV + k * NUV + u] + rk_u[e];
        ent[p2] = make_float2(__int_as_float(i), nm);
    }
}

// ---------------- fused gather-aggregate + transform + hetero combine --------
// One launch covers both directions. Features are fp16 rows (64 half = 128 B).
// Per relation k: stage W_k in LDS; each wave gathers its 4 dst nodes
// concurrently, 8 edge-slots per node in flight (unroll x2), lanes =
// 4 edge-subgroups x 16 half4-cols; shfl_xor reduce; 256 threads = 16 rows x
// 16 col-groups compute y_k = acc @ W_k + b_k; combine across k in registers.
// MODE 0: relu(max(y_k)), MODE 1: sum(y_k). HOUT: write half rows else float.
template <int MODE, bool HOUT>
__global__ __launch_bounds__(256, 4) void k_agg(const __half* __restrict__ x_i,  // srcs for item-side (users)
                                                const __half* __restrict__ x_u,  // srcs for user-side (items)
                                                const float2* __restrict__ ent,
                                                const int* __restrict__ S,
                                                const float* __restrict__ Wall,  // [6,64,64]
                                                const float* __restrict__ ball,  // [6,64]
                                                void* __restrict__ out_i,
                                                void* __restrict__ out_u) {
    __shared__ float sW[4096];        // 64x64 weights for current relation
    __shared__ float sAcc[16 * 68];   // 16 rows, stride 68 (bank-conflict pad)
    const int nb_i = NIV / 16;
    bool item_side = blockIdx.x < nb_i;
    const __half* x = item_side ? x_i : x_u;
    const float* Wb = item_side ? Wall : Wall + 3 * 4096;
    const float* bb = item_side ? ball : ball + 192;
    void* outp      = item_side ? out_i : out_u;
    int n_dst       = item_side ? NIV : NUV;
    int seg_base    = item_side ? 0 : 3 * NIV;
    int d0          = (item_side ? blockIdx.x : (blockIdx.x - nb_i)) * 16;

    int wave = threadIdx.x >> 6;
    int lane = threadIdx.x & 63;
    int eg   = lane >> 4;             // edge subgroup 0..3
    int fq   = lane & 15;             // half4 column group 0..15
    int r2 = threadIdx.x >> 4;        // 0..15 row for transform phase
    int g  = threadIdx.x & 15;        // col group (4 cols)

    float4 res = make_float4(0.f, 0.f, 0.f, 0.f);
    for (int k = 0; k < 3; k++) {
        __syncthreads();  // protect sW/sAcc from previous iteration's readers
        // issue segment-bound loads early (overlap with W staging)
        int idx = seg_base + k * n_dst + d0 + wave * 4;
        int v0 = S[idx], v1 = S[idx + 1], v2 = S[idx + 2], v3 = S[idx + 3], v4 = S[idx + 4];
        // stage W_k
        {
            const float4* wsrc = (const float4*)(Wb + (size_t)k * 4096);
            float4* wdst = (float4*)sW;
            #pragma unroll
            for (int i = 0; i < 4; i++) wdst[threadIdx.x + 256 * i] = wsrc[threadIdx.x + 256 * i];
        }
        // gather-aggregate: this wave's 4 nodes concurrently, 8 slots/node
        {
            int st[4] = {v0, v1, v2, v3};
            int en[4] = {v1, v2, v3, v4};
            int maxlen = max(max(v1 - v0, v2 - v1), max(v3 - v2, v4 - v3));
            int maxit = (maxlen + 3) >> 2;
            float4 a[4];
            #pragma unroll
            for (int n = 0; n < 4; n++) a[n] = make_float4(0.f, 0.f, 0.f, 0.f);
            for (int it = 0; it < maxit; it += 2) {
                #pragma unroll
                for (int n = 0; n < 4; n++) {
                    int p0 = st[n] + (it << 2) + eg;
                    if (p0 < en[n]) {
                        float2 e = ent[p0];
                        int s = __float_as_int(e.x);
                        float2 raw = *(const float2*)(x + (size_t)s * 64 + fq * 4);
                        float2 f0 = __half22float2(*reinterpret_cast<__half2*>(&raw.x));
                        float2 f1 = __half22float2(*reinterpret_cast<__half2*>(&raw.y));
                        a[n].x = fmaf(f0.x, e.y, a[n].x);
                        a[n].y = fmaf(f0.y, e.y, a[n].y);
                        a[n].z = fmaf(f1.x, e.y, a[n].z);
                        a[n].w = fmaf(f1.y, e.y, a[n].w);
                    }
                    int p1 = p0 + 4;
                    if (p1 < en[n]) {
                        float2 e = ent[p1];
                        int s = __float_as_int(e.x);
                        float2 raw = *(const float2*)(x + (size_t)s * 64 + fq * 4);
                        float2 f0 = __half22float2(*reinterpret_cast<__half2*>(&raw.x));
                        float2 f1 = __half22float2(*reinterpret_cast<__half2*>(&raw.y));
                        a[n].x = fmaf(f0.x, e.y, a[n].x);
                        a[n].y = fmaf(f0.y, e.y, a[n].y);
                        a[n].z = fmaf(f1.x, e.y, a[n].z);
                        a[n].w = fmaf(f1.y, e.y, a[n].w);
                    }
                }
            }
            // reduce across the 4 edge-subgroups (lanes l, l^16, l^32, l^48)
            #pragma unroll
            for (int n = 0; n < 4; n++) {
                #pragma unroll
                for (int off = 16; off < 64; off <<= 1) {
                    a[n].x += __shfl_xor(a[n].x, off, 64);
                    a[n].y += __shfl_xor(a[n].y, off, 64);
                    a[n].z += __shfl_xor(a[n].z, off, 64);
                    a[n].w += __shfl_xor(a[n].w, off, 64);
                }
                if (lane < 16)
                    *(float4*)&sAcc[(wave * 4 + n) * 68 + fq * 4] = a[n];
            }
        }
        __syncthreads();
        // transform: y_k = acc @ W_k + b_k for this thread's (row r2, cols g*4..+3)
        float4 y = *(const float4*)&bb[k * 64 + g * 4];
        #pragma unroll
        for (int c = 0; c < 64; c++) {
            float a = sAcc[r2 * 68 + c];
            float4 w = *(const float4*)&sW[c * 64 + g * 4];
            y.x = fmaf(a, w.x, y.x);
            y.y = fmaf(a, w.y, y.y);
            y.z = fmaf(a, w.z, y.z);
            y.w = fmaf(a, w.w, y.w);
        }
        if (k == 0) {
            res = y;
        } else if (MODE == 0) {
            res.x = fmaxf(res.x, y.x); res.y = fmaxf(res.y, y.y);
            res.z = fmaxf(res.z, y.z); res.w = fmaxf(res.w, y.w);
        } else {
            res.x += y.x; res.y += y.y; res.z += y.z; res.w += y.w;
        }
    }
    if (MODE == 0) {
        res.x = fmaxf(res.x, 0.f); res.y = fmaxf(res.y, 0.f);
        res.z = fmaxf(res.z, 0.f); res.w = fmaxf(res.w, 0.f);
    }
    if (HOUT) {
        H4 o;
        o.a = __floats2half2_rn(res.x, res.y);
        o.b = __floats2half2_rn(res.z, res.w);
        *(H4*)((__half*)outp + (size_t)(d0 + r2) * 64 + g * 4) = o;
    } else {
        *(float4*)((float*)outp + (size_t)(d0 + r2) * 64 + g * 4) = res;
    }
}

// ---------------- decoder: 16 queries per block, tile GEMM -------------------
__global__ __launch_bounds__(256) void k_decoder(const float* __restrict__ xu,
                                                 const float* __restrict__ xi,
                                                 const int* __restrict__ uids,
                                                 const int* __restrict__ iids,
                                                 const float* __restrict__ w1,
                                                 const float* __restrict__ b1,
                                                 const float* __restrict__ w2,
                                                 const float* __restrict__ b2,
                                                 float* __restrict__ out) {
    __shared__ float sW1[128 * 64];   // 32 KB
    __shared__ float sE[16 * 132];    // 16 gathered 128-dim rows, padded
    __shared__ float sH[16 * 68];     // hidden after relu, padded
    __shared__ float sW2[64 * 4];
    // stage weights
    {
        const float4* wsrc = (const float4*)w1;
        float4* wdst = (float4*)sW1;
        #pragma unroll
        for (int i = 0; i < 8; i++) wdst[threadIdx.x + 256 * i] = wsrc[threadIdx.x + 256 * i];
        if (threadIdx.x < 64) {
            float4 v = ((const float4*)w2)[threadIdx.x];
            ((float4*)sW2)[threadIdx.x] = v;
        }
    }
    int q0 = blockIdx.x * 16;
    // gather 16 query rows (user 64 + item 64) into sE
    {
        int q = threadIdx.x >> 4;     // 0..15
        int p = threadIdx.x & 15;     // 0..15 float4s
        int uid = uids[q0 + q];
        int iid = iids[q0 + q];
        float4 vu = *(const float4*)&xu[(size_t)uid * 64 + p * 4];
        float4 vi = *(const float4*)&xi[(size_t)iid * 64 + p * 4];
        *(float4*)&sE[q * 132 + p * 4] = vu;
        *(float4*)&sE[q * 132 + 64 + p * 4] = vi;
    }
    __syncthreads();
    // layer 1: h = relu(E @ W1 + b1); thread = (row r, col group g)
    {
        int r = threadIdx.x >> 4;
        int g = threadIdx.x & 15;
        float4 y = *(const float4*)&b1[g * 4];
        #pragma unroll
        for (int c = 0; c < 128; c++) {
            float a = sE[r * 132 + c];
            float4 w = *(const float4*)&sW1[c * 64 + g * 4];
            y.x = fmaf(a, w.x, y.x);
            y.y = fmaf(a, w.y, y.y);
            y.z = fmaf(a, w.z, y.z);
            y.w = fmaf(a, w.w, y.w);
        }
        y.x = fmaxf(y.x, 0.f); y.y = fmaxf(y.y, 0.f);
        y.z = fmaxf(y.z, 0.f); y.w = fmaxf(y.w, 0.f);
        *(float4*)&sH[r * 68 + g * 4] = y;
    }
    __syncthreads();
    // layer 2: out = H @ W2 + b2 ; 64 threads, one (query, out-col) each
    if (threadIdx.x < 64) {
        int q = threadIdx.x >> 2;
        int oc = threadIdx.x & 3;
        float acc = b2[oc];
        #pragma unroll
        for (int c = 0; c < 64; c++)
            acc = fmaf(sH[q * 68 + c], sW2[c * 4 + oc], acc);
        out[(size_t)(q0 + q) * 4 + oc] = acc;
    }
}

extern "C" void kernel_launch(void* const* d_in, const int* in_sizes, int n_in,
                              void* d_out, int out_size, void* d_ws, size_t ws_size,
                              hipStream_t stream) {
    const float* user_emb = (const float*)d_in[0];
    const float* item_emb = (const float*)d_in[1];
    const float* W1 = (const float*)d_in[2];
    const float* b1 = (const float*)d_in[3];
    const float* W2 = (const float*)d_in[4];
    const float* b2 = (const float*)d_in[5];
    const float* dw1 = (const float*)d_in[6];
    const float* db1 = (const float*)d_in[7];
    const float* dw2 = (const float*)d_in[8];
    const float* db2 = (const float*)d_in[9];
    const int* edges[3] = {(const int*)d_in[10], (const int*)d_in[11], (const int*)d_in[12]};
    const int* uids = (const int*)d_in[13];
    const int* iids = (const int*)d_in[14];
    float* out = (float*)d_out;
    (void)in_sizes; (void)n_in; (void)out_size; (void)ws_size;

    // workspace layout (all region sizes multiples of 16 B)
    char* base = (char*)d_ws;
    size_t off = 0;
    int*    cnt  = (int*)(base + off);    off += (size_t)NC * 4;
    int*    S    = (int*)(base + off);    off += (size_t)(NC + 8) * 4;
    int*    bsum = (int*)(base + off);    off += (size_t)4096 * 4;
    float*  invs = (float*)(base + off);  off += (size_t)NC * 4;
    int*    rki  = (int*)(base + off);    off += (size_t)3 * EV * 4;
    int*    rku  = (int*)(base + off);    off += (size_t)3 * EV * 4;
    float2* ent  = (float2*)(base + off); off += (size_t)6 * EV * 8;
    __half* he_u = (__half*)(base + off); off += (size_t)NUV * 64 * 2;
    __half* he_i = (__half*)(base + off); off += (size_t)NIV * 64 * 2;
    __half* xu1h = (__half*)(base + off); off += (size_t)NUV * 64 * 2;
    __half* xi1h = (__half*)(base + off); off += (size_t)NIV * 64 * 2;
    float*  xu2  = (float*)(base + off);  off += (size_t)NUV * 64 * 4;
    float*  xi2  = (float*)(base + off);  off += (size_t)NIV * 64 * 4;

    const int EB  = (EV + 255) / 256;       // 3907
    const int SB1 = (NC + 255) / 256;       // 3516
    const int AGGB = NIV / 16 + NUV / 16;   // 18750

    // ---- fp16 feature tables ----
    k_tohalf<<<(NUV * 64 / 4 + 255) / 256, 256, 0, stream>>>(user_emb, he_u, NUV * 64 / 4);
    k_tohalf<<<(NIV * 64 / 4 + 255) / 256, 256, 0, stream>>>(item_emb, he_i, NIV * 64 / 4);

    // ---- CSR build ----
    hipMemsetAsync(cnt, 0, (size_t)NC * 4, stream);
    for (int k = 0; k < 3; k++)
        k_count<<<EB, 256, 0, stream>>>(edges[k], edges[k] + EV, cnt,
                                        rki + (size_t)k * EV, rku + (size_t)k * EV, k);
    k_invf<<<SB1, 256, 0, stream>>>(cnt, invs);
    k_scan1<<<SB1, 256, 0, stream>>>(cnt, S, bsum);
    k_scan2<<<1, 64, 0, stream>>>(bsum, SB1);
    k_scan3<<<SB1, 256, 0, stream>>>(S, bsum);
    for (int k = 0; k < 3; k++)
        k_fill<<<EB, 256, 0, stream>>>(edges[k], edges[k] + EV, invs, S,
                                       rki + (size_t)k * EV, rku + (size_t)k * EV, ent, k);

    // ---- layer 1 (max across relations, then relu): both directions ----
    k_agg<0, true><<<AGGB, 256, 0, stream>>>(he_u, he_i, ent, S, W1, b1, xi1h, xu1h);
    // ---- layer 2 (sum across relations): both directions ----
    k_agg<1, false><<<AGGB, 256, 0, stream>>>(xu1h, xi1h, ent, S, W2, b2, xi2, xu2);

    // ---- decoder ----
    k_decoder<<<NQV / 16, 256, 0, stream>>>(xu2, xi2, uids, iids,
                                            dw1, db1, dw2, db2, out);
}

// Round 5
// 1444.287 us; speedup vs baseline: 2.4897x; 1.0183x over previous
//
#include <hip/hip_runtime.h>
#include <hip/hip_fp16.h>
#include <math.h>

#define NUV 200000
#define NIV 100000
#define EV  1000000
#define NQV 100000
#define NC  (3 * NIV + 3 * NUV)   // 900000 concatenated degree/bucket counters
// bucket layout: [rel0 items][rel1 items][rel2 items][rel0 users][rel1 users][rel2 users]

struct alignas(8) H4 { __half2 a, b; };

// ---------------- fp32 -> fp16 table conversion ------------------------------
__global__ __launch_bounds__(256) void k_tohalf(const float* __restrict__ in,
                                                __half* __restrict__ out, int n4) {
    int i = blockIdx.x * 256 + threadIdx.x;
    if (i < n4) {
        float4 v = ((const float4*)in)[i];
        H4 o;
        o.a = __floats2half2_rn(v.x, v.y);
        o.b = __floats2half2_rn(v.z, v.w);
        ((H4*)out)[i] = o;
    }
}

// ---------------- histogram + in-bucket rank (all 3 relations) ---------------
__global__ __launch_bounds__(256) void k_count(const int* __restrict__ e0,
                                               const int* __restrict__ e1,
                                               const int* __restrict__ e2,
                                               int* __restrict__ cnt,
                                               int* __restrict__ rk_i,
                                               int* __restrict__ rk_u) {
    int k = blockIdx.y;
    const int* ed = (k == 0) ? e0 : (k == 1) ? e1 : e2;
    int e = blockIdx.x * 256 + threadIdx.x;
    if (e < EV) {
        int u = ed[e], i = ed[EV + e];
        rk_i[(size_t)k * EV + e] = atomicAdd(&cnt[k * NIV + i], 1);
        rk_u[(size_t)k * EV + e] = atomicAdd(&cnt[3 * NIV + k * NUV + u], 1);
    }
}

// ---------------- counts -> 1/sqrt(deg) --------------------------------------
__global__ __launch_bounds__(256) void k_invf(const int* __restrict__ cnt,
                                              float* __restrict__ invs) {
    int i = blockIdx.x * 256 + threadIdx.x;
    if (i < NC) {
        int c = cnt[i];
        invs[i] = (c > 0) ? (1.0f / sqrtf((float)c)) : 0.0f;
    }
}

// ---------------- scan stage 1: per-256 tile exclusive scan ------------------
__global__ __launch_bounds__(256) void k_scan1(const int* __restrict__ cnt,
                                               int* __restrict__ S,
                                               int* __restrict__ bsum) {
    __shared__ int tmp[256];
    int idx = blockIdx.x * 256 + threadIdx.x;
    int v = (idx < NC) ? cnt[idx] : 0;
    tmp[threadIdx.x] = v;
    __syncthreads();
    for (int off = 1; off < 256; off <<= 1) {
        int t = (threadIdx.x >= off) ? tmp[threadIdx.x - off] : 0;
        __syncthreads();
        tmp[threadIdx.x] += t;
        __syncthreads();
    }
    if (idx < NC) S[idx] = tmp[threadIdx.x] - v;
    if (threadIdx.x == 255) bsum[blockIdx.x] = tmp[255];
}

// ---------------- scan stage 2: single-wave scan of block sums ---------------
__global__ __launch_bounds__(64) void k_scan2(int* __restrict__ bsum, int nb) {
    int lane = threadIdx.x;
    int carry = 0;
    for (int base = 0; base < nb; base += 64) {
        int i = base + lane;
        int v = (i < nb) ? bsum[i] : 0;
        int orig = v;
        #pragma unroll
        for (int off = 1; off < 64; off <<= 1) {
            int t = __shfl_up(v, off, 64);
            if (lane >= off) v += t;
        }
        if (i < nb) bsum[i] = carry + v - orig;  // exclusive
        carry += __shfl(v, 63, 64);
    }
}

// ---------------- scan stage 3: add block offsets, write sentinel ------------
__global__ __launch_bounds__(256) void k_scan3(int* __restrict__ S,
                                               const int* __restrict__ bsum) {
    int idx = blockIdx.x * 256 + threadIdx.x;
    if (idx < NC) S[idx] += bsum[blockIdx.x];
    if (idx == 0) S[NC] = 6 * EV;
}

// ---------------- fill CSR entries via precomputed ranks (no atomics) --------
__global__ __launch_bounds__(256) void k_fill(const int* __restrict__ e0,
                                              const int* __restrict__ e1,
                                              const int* __restrict__ e2,
                                              const float* __restrict__ invs,
                                              const int* __restrict__ S,
                                              const int* __restrict__ rk_i,
                                              const int* __restrict__ rk_u,
                                              float2* __restrict__ ent) {
    int k = blockIdx.y;
    const int* ed = (k == 0) ? e0 : (k == 1) ? e1 : e2;
    int e = blockIdx.x * 256 + threadIdx.x;
    if (e < EV) {
        int u = ed[e], i = ed[EV + e];
        float nm = invs[k * NIV + i] * invs[3 * NIV + k * NUV + u];
        int p1 = S[k * NIV + i] + rk_i[(size_t)k * EV + e];
        ent[p1] = make_float2(__int_as_float(u), nm);
        int p2 = S[3 * NIV + k * NUV + u] + rk_u[(size_t)k * EV + e];
        ent[p2] = make_float2(__int_as_float(i), nm);
    }
}

// ---------------- fused gather-aggregate + transform + hetero combine --------
// One launch covers both directions. Features are fp16 rows (64 half = 128 B).
// Per relation k: stage W_k in LDS; each wave gathers its 4 dst nodes
// concurrently with lanes = 8 edge-subgroups x 8 col-lanes (16 B each) ->
// 32 independent row loads in flight per wave; 3-level shfl_xor reduce;
// 256 threads = 16 rows x 16 col-groups compute y_k = acc @ W_k + b_k;
// combine across k in registers. MODE 0: relu(max), MODE 1: sum.
template <int MODE, bool HOUT>
__global__ __launch_bounds__(256, 4) void k_agg(const __half* __restrict__ x_i,  // srcs for item-side (users)
                                                const __half* __restrict__ x_u,  // srcs for user-side (items)
                                                const float2* __restrict__ ent,
                                                const int* __restrict__ S,
                                                const float* __restrict__ Wall,  // [6,64,64]
                                                const float* __restrict__ ball,  // [6,64]
                                                void* __restrict__ out_i,
                                                void* __restrict__ out_u) {
    __shared__ float sW[4096];        // 64x64 weights for current relation
    __shared__ float sAcc[16 * 68];   // 16 rows, stride 68 (bank-conflict pad)
    const int nb_i = NIV / 16;
    bool item_side = blockIdx.x < nb_i;
    const __half* x = item_side ? x_i : x_u;
    const float* Wb = item_side ? Wall : Wall + 3 * 4096;
    const float* bb = item_side ? ball : ball + 192;
    void* outp      = item_side ? out_i : out_u;
    int n_dst       = item_side ? NIV : NUV;
    int seg_base    = item_side ? 0 : 3 * NIV;
    int d0          = (item_side ? blockIdx.x : (blockIdx.x - nb_i)) * 16;

    int wave = threadIdx.x >> 6;
    int lane = threadIdx.x & 63;
    int eg   = lane >> 3;             // edge subgroup 0..7
    int fh   = lane & 7;              // 16-byte column group 0..7 (8 halves)
    int r2 = threadIdx.x >> 4;        // 0..15 row for transform phase
    int g  = threadIdx.x & 15;        // col group (4 cols)

    float4 res = make_float4(0.f, 0.f, 0.f, 0.f);
    for (int k = 0; k < 3; k++) {
        __syncthreads();  // protect sW/sAcc from previous iteration's readers
        // segment bounds for this wave's 4 nodes
        int idx = seg_base + k * n_dst + d0 + wave * 4;
        int v0 = S[idx], v1 = S[idx + 1], v2 = S[idx + 2], v3 = S[idx + 3], v4 = S[idx + 4];
        // stage W_k
        {
            const float4* wsrc = (const float4*)(Wb + (size_t)k * 4096);
            float4* wdst = (float4*)sW;
            #pragma unroll
            for (int i = 0; i < 4; i++) wdst[threadIdx.x + 256 * i] = wsrc[threadIdx.x + 256 * i];
        }
        // gather-aggregate: 4 nodes x 8 edge-slots in flight
        {
            int st[4] = {v0, v1, v2, v3};
            int en[4] = {v1, v2, v3, v4};
            int maxlen = max(max(v1 - v0, v2 - v1), max(v3 - v2, v4 - v3));
            int maxit = (maxlen + 7) >> 3;
            float af[4][8];
            #pragma unroll
            for (int n = 0; n < 4; n++)
                #pragma unroll
                for (int j = 0; j < 8; j++) af[n][j] = 0.f;
            for (int it = 0; it < maxit; it++) {
                #pragma unroll
                for (int n = 0; n < 4; n++) {
                    int p = st[n] + (it << 3) + eg;
                    if (p < en[n]) {
                        float2 e = ent[p];
                        int s = __float_as_int(e.x);
                        float4 raw = *(const float4*)(x + (size_t)s * 64 + fh * 8);
                        const __half2* h2 = (const __half2*)&raw;
                        #pragma unroll
                        for (int j = 0; j < 4; j++) {
                            float2 f = __half22float2(h2[j]);
                            af[n][2 * j]     = fmaf(f.x, e.y, af[n][2 * j]);
                            af[n][2 * j + 1] = fmaf(f.y, e.y, af[n][2 * j + 1]);
                        }
                    }
                }
            }
            // reduce across the 8 edge-subgroups (xor 8,16,32)
            #pragma unroll
            for (int n = 0; n < 4; n++) {
                #pragma unroll
                for (int j = 0; j < 8; j++) {
                    af[n][j] += __shfl_xor(af[n][j], 8, 64);
                    af[n][j] += __shfl_xor(af[n][j], 16, 64);
                    af[n][j] += __shfl_xor(af[n][j], 32, 64);
                }
                if (lane < 8) {
                    int row = wave * 4 + n;
                    *(float4*)&sAcc[row * 68 + lane * 8] =
                        make_float4(af[n][0], af[n][1], af[n][2], af[n][3]);
                    *(float4*)&sAcc[row * 68 + lane * 8 + 4] =
                        make_float4(af[n][4], af[n][5], af[n][6], af[n][7]);
                }
            }
        }
        __syncthreads();
        // transform: y_k = acc @ W_k + b_k for this thread's (row r2, cols g*4..+3)
        float4 y = *(const float4*)&bb[k * 64 + g * 4];
        #pragma unroll
        for (int c = 0; c < 64; c++) {
            float a = sAcc[r2 * 68 + c];
            float4 w = *(const float4*)&sW[c * 64 + g * 4];
            y.x = fmaf(a, w.x, y.x);
            y.y = fmaf(a, w.y, y.y);
            y.z = fmaf(a, w.z, y.z);
            y.w = fmaf(a, w.w, y.w);
        }
        if (k == 0) {
            res = y;
        } else if (MODE == 0) {
            res.x = fmaxf(res.x, y.x); res.y = fmaxf(res.y, y.y);
            res.z = fmaxf(res.z, y.z); res.w = fmaxf(res.w, y.w);
        } else {
            res.x += y.x; res.y += y.y; res.z += y.z; res.w += y.w;
        }
    }
    if (MODE == 0) {
        res.x = fmaxf(res.x, 0.f); res.y = fmaxf(res.y, 0.f);
        res.z = fmaxf(res.z, 0.f); res.w = fmaxf(res.w, 0.f);
    }
    if (HOUT) {
        H4 o;
        o.a = __floats2half2_rn(res.x, res.y);
        o.b = __floats2half2_rn(res.z, res.w);
        *(H4*)((__half*)outp + (size_t)(d0 + r2) * 64 + g * 4) = o;
    } else {
        *(float4*)((float*)outp + (size_t)(d0 + r2) * 64 + g * 4) = res;
    }
}

// ---------------- decoder: 16 queries per block, tile GEMM -------------------
__global__ __launch_bounds__(256) void k_decoder(const float* __restrict__ xu,
                                                 const float* __restrict__ xi,
                                                 const int* __restrict__ uids,
                                                 const int* __restrict__ iids,
                                                 const float* __restrict__ w1,
                                                 const float* __restrict__ b1,
                                                 const float* __restrict__ w2,
                                                 const float* __restrict__ b2,
                                                 float* __restrict__ out) {
    __shared__ float sW1[128 * 64];   // 32 KB
    __shared__ float sE[16 * 132];    // 16 gathered 128-dim rows, padded
    __shared__ float sH[16 * 68];     // hidden after relu, padded
    __shared__ float sW2[64 * 4];
    // stage weights
    {
        const float4* wsrc = (const float4*)w1;
        float4* wdst = (float4*)sW1;
        #pragma unroll
        for (int i = 0; i < 8; i++) wdst[threadIdx.x + 256 * i] = wsrc[threadIdx.x + 256 * i];
        if (threadIdx.x < 64) {
            float4 v = ((const float4*)w2)[threadIdx.x];
            ((float4*)sW2)[threadIdx.x] = v;
        }
    }
    int q0 = blockIdx.x * 16;
    // gather 16 query rows (user 64 + item 64) into sE
    {
        int q = threadIdx.x >> 4;     // 0..15
        int p = threadIdx.x & 15;     // 0..15 float4s
        int uid = uids[q0 + q];
        int iid = iids[q0 + q];
        float4 vu = *(const float4*)&xu[(size_t)uid * 64 + p * 4];
        float4 vi = *(const float4*)&xi[(size_t)iid * 64 + p * 4];
        *(float4*)&sE[q * 132 + p * 4] = vu;
        *(float4*)&sE[q * 132 + 64 + p * 4] = vi;
    }
    __syncthreads();
    // layer 1: h = relu(E @ W1 + b1); thread = (row r, col group g)
    {
        int r = threadIdx.x >> 4;
        int g = threadIdx.x & 15;
        float4 y = *(const float4*)&b1[g * 4];
        #pragma unroll
        for (int c = 0; c < 128; c++) {
            float a = sE[r * 132 + c];
            float4 w = *(const float4*)&sW1[c * 64 + g * 4];
            y.x = fmaf(a, w.x, y.x);
            y.y = fmaf(a, w.y, y.y);
            y.z = fmaf(a, w.z, y.z);
            y.w = fmaf(a, w.w, y.w);
        }
        y.x = fmaxf(y.x, 0.f); y.y = fmaxf(y.y, 0.f);
        y.z = fmaxf(y.z, 0.f); y.w = fmaxf(y.w, 0.f);
        *(float4*)&sH[r * 68 + g * 4] = y;
    }
    __syncthreads();
    // layer 2: out = H @ W2 + b2 ; 64 threads, one (query, out-col) each
    if (threadIdx.x < 64) {
        int q = threadIdx.x >> 2;
        int oc = threadIdx.x & 3;
        float acc = b2[oc];
        #pragma unroll
        for (int c = 0; c < 64; c++)
            acc = fmaf(sH[q * 68 + c], sW2[c * 4 + oc], acc);
        out[(size_t)(q0 + q) * 4 + oc] = acc;
    }
}

extern "C" void kernel_launch(void* const* d_in, const int* in_sizes, int n_in,
                              void* d_out, int out_size, void* d_ws, size_t ws_size,
                              hipStream_t stream) {
    const float* user_emb = (const float*)d_in[0];
    const float* item_emb = (const float*)d_in[1];
    const float* W1 = (const float*)d_in[2];
    const float* b1 = (const float*)d_in[3];
    const float* W2 = (const float*)d_in[4];
    const float* b2 = (const float*)d_in[5];
    const float* dw1 = (const float*)d_in[6];
    const float* db1 = (const float*)d_in[7];
    const float* dw2 = (const float*)d_in[8];
    const float* db2 = (const float*)d_in[9];
    const int* e0 = (const int*)d_in[10];
    const int* e1 = (const int*)d_in[11];
    const int* e2 = (const int*)d_in[12];
    const int* uids = (const int*)d_in[13];
    const int* iids = (const int*)d_in[14];
    float* out = (float*)d_out;
    (void)in_sizes; (void)n_in; (void)out_size; (void)ws_size;

    // workspace layout (all region sizes multiples of 16 B)
    char* base = (char*)d_ws;
    size_t off = 0;
    int*    cnt  = (int*)(base + off);    off += (size_t)NC * 4;
    int*    S    = (int*)(base + off);    off += (size_t)(NC + 8) * 4;
    int*    bsum = (int*)(base + off);    off += (size_t)4096 * 4;
    float*  invs = (float*)(base + off);  off += (size_t)NC * 4;
    int*    rki  = (int*)(base + off);    off += (size_t)3 * EV * 4;
    int*    rku  = (int*)(base + off);    off += (size_t)3 * EV * 4;
    float2* ent  = (float2*)(base + off); off += (size_t)6 * EV * 8;
    __half* he_u = (__half*)(base + off); off += (size_t)NUV * 64 * 2;
    __half* he_i = (__half*)(base + off); off += (size_t)NIV * 64 * 2;
    __half* xu1h = (__half*)(base + off); off += (size_t)NUV * 64 * 2;
    __half* xi1h = (__half*)(base + off); off += (size_t)NIV * 64 * 2;
    float*  xu2  = (float*)(base + off);  off += (size_t)NUV * 64 * 4;
    float*  xi2  = (float*)(base + off);  off += (size_t)NIV * 64 * 4;

    const int EB  = (EV + 255) / 256;       // 3907
    const int SB1 = (NC + 255) / 256;       // 3516
    const int AGGB = NIV / 16 + NUV / 16;   // 18750

    // ---- fp16 feature tables ----
    k_tohalf<<<(NUV * 64 / 4 + 255) / 256, 256, 0, stream>>>(user_emb, he_u, NUV * 64 / 4);
    k_tohalf<<<(NIV * 64 / 4 + 255) / 256, 256, 0, stream>>>(item_emb, he_i, NIV * 64 / 4);

    // ---- CSR build ----
    hipMemsetAsync(cnt, 0, (size_t)NC * 4, stream);
    k_count<<<dim3(EB, 3), 256, 0, stream>>>(e0, e1, e2, cnt, rki, rku);
    k_invf<<<SB1, 256, 0, stream>>>(cnt, invs);
    k_scan1<<<SB1, 256, 0, stream>>>(cnt, S, bsum);
    k_scan2<<<1, 64, 0, stream>>>(bsum, SB1);
    k_scan3<<<SB1, 256, 0, stream>>>(S, bsum);
    k_fill<<<dim3(EB, 3), 256, 0, stream>>>(e0, e1, e2, invs, S, rki, rku, ent);

    // ---- layer 1 (max across relations, then relu): both directions ----
    k_agg<0, true><<<AGGB, 256, 0, stream>>>(he_u, he_i, ent, S, W1, b1, xi1h, xu1h);
    // ---- layer 2 (sum across relations): both directions ----
    k_agg<1, false><<<AGGB, 256, 0, stream>>>(xu1h, xi1h, ent, S, W2, b2, xi2, xu2);

    // ---- decoder ----
    k_decoder<<<NQV / 16, 256, 0, stream>>>(xu2, xi2, uids, iids,
                                            dw1, db1, dw2, db2, out);
}